// Round 2
// baseline (917.871 us; speedup 1.0000x reference)
//
#include <hip/hip_runtime.h>
#include <hip/hip_cooperative_groups.h>
#include <stdint.h>
#include <math.h>

namespace cg = cooperative_groups;

#define NN 8192        // nodes
#define NE 262144      // edges
#define WPR 256        // 32-bit words per dense adjacency row
#define CAP 96         // ELL slots/row; max unique degree ~56, P(overflow)~1e-15

struct TFKey { uint32_t a, b; };

// JAX threefry2x32 (rot 13,15,26,6 / 17,29,16,24; 20 rounds)
__host__ __device__ static inline void tf2x32(uint32_t k0, uint32_t k1,
                                              uint32_t x0, uint32_t x1,
                                              uint32_t* o0, uint32_t* o1) {
  uint32_t ks2 = k0 ^ k1 ^ 0x1BD11BDAu;
#define TF_ROT(x, r) (((x) << (r)) | ((x) >> (32 - (r))))
#define TF_R(r) { x0 += x1; x1 = TF_ROT(x1, r); x1 ^= x0; }
  x0 += k0; x1 += k1;
  TF_R(13) TF_R(15) TF_R(26) TF_R(6)
  x0 += k1;  x1 += ks2 + 1u;
  TF_R(17) TF_R(29) TF_R(16) TF_R(24)
  x0 += ks2; x1 += k0 + 2u;
  TF_R(13) TF_R(15) TF_R(26) TF_R(6)
  x0 += k0;  x1 += k1 + 3u;
  TF_R(17) TF_R(29) TF_R(16) TF_R(24)
  x0 += k1;  x1 += ks2 + 4u;
  TF_R(13) TF_R(15) TF_R(26) TF_R(6)
  x0 += ks2; x1 += k0 + 5u;
  *o0 = x0; *o1 = x1;
#undef TF_R
#undef TF_ROT
}

// JAX partitionable 32-bit random_bits at flat index n: bits = o0^o1 @ (0,n);
// uniform f32 = bitcast((bits>>9)|0x3f800000) - 1.0f  (exact 2^-23 grid)
__device__ static inline float tf_uniform(TFKey k, uint32_t n) {
  uint32_t o0, o1;
  tf2x32(k.a, k.b, 0u, n, &o0, &o1);
  uint32_t bits = o0 ^ o1;
  return __uint_as_float((bits >> 9) | 0x3f800000u) - 1.0f;
}

// ======================= fused cooperative kernel ==========================

struct Params {
  const float* x; const float* W0; const float* b0;
  const float* W1; const float* b1; const float* W2; const float* b2;
  const int* ei; float* out;
  uint32_t* dense; float* h; float* z;
  uint32_t* deg; uint16_t* cols; uint8_t* mask; float* dinv; uint32_t* flag;
  TFKey kd0, kb0, kd1, kb1, kd2;
};

// H = A@W, f64 acc -> f32 round (bit-identical to prior verified kernels)
template<int K, int N>
__device__ __forceinline__ void gemm_ph(const float* __restrict__ A,
                                        const float* __restrict__ Wb,
                                        float* __restrict__ H, int tid, int tot) {
  for (int t = tid; t < NN * N; t += tot) {
    int i = t / N, c = t % N;
    double a0 = 0.0, a1 = 0.0;
#pragma unroll 8
    for (int k = 0; k < K; k += 2) {
      a0 += (double)A[(size_t)i * K + k] * (double)Wb[(size_t)k * N + c];
      a1 += (double)A[(size_t)i * K + k + 1] * (double)Wb[(size_t)(k + 1) * N + c];
    }
    H[t] = (float)(a0 + a1);
  }
}

// z_i = dropout(relu(sum_j f32(di*dj)*h_j + f32(di*di)*h_i + b)); wave-per-row
template<int D>
__device__ __forceinline__ void agg_ph(const uint16_t* __restrict__ cols,
                                       const uint32_t* __restrict__ deg,
                                       const uint8_t* __restrict__ mask,
                                       const float* __restrict__ h,
                                       const float* __restrict__ dinv,
                                       const float* __restrict__ bias,
                                       TFKey kd, float* __restrict__ zout,
                                       int wid, int nw, int lane) {
  bool act = lane < D;
  for (int i = wid; i < NN; i += nw) {
    float di = dinv[i];
    uint32_t du = deg[i];
    uint32_t d = du < (uint32_t)CAP ? du : (uint32_t)CAP;
    const uint16_t* cr = cols + (size_t)i * CAP;
    const uint8_t* mr = mask ? mask + (size_t)i * CAP : (const uint8_t*)nullptr;
    double a0 = 0.0, a1 = 0.0;
    uint32_t s = 0;
    for (; s + 1 < d; s += 2) {               // 2 accumulators: half the chain
      int j0 = cr[s], j1 = cr[s + 1];
      bool m0 = !mr || mr[s], m1 = !mr || mr[s + 1];
      if (act) {
        if (m0) { float c0 = di * dinv[j0]; a0 += (double)c0 * (double)h[(size_t)j0 * D + lane]; }
        if (m1) { float c1 = di * dinv[j1]; a1 += (double)c1 * (double)h[(size_t)j1 * D + lane]; }
      }
    }
    if (s < d && (!mr || mr[s]) && act) {
      int j = cr[s];
      float c = di * dinv[j];
      a0 += (double)c * (double)h[(size_t)j * D + lane];
    }
    if (act) {
      double acc = a0 + a1;
      float cI = di * di;                     // +I diagonal term, f32
      acc += (double)cI * (double)h[(size_t)i * D + lane];
      float sv = (float)acc;                  // matmul result rounded f32
      float pre = fmaxf(sv + bias[lane], 0.0f);
      float u = tf_uniform(kd, (uint32_t)(i * D + lane));
      zout[(size_t)i * D + lane] = (u < 0.9f) ? (pre / 0.9f) : 0.0f;
    }
  }
}

// wave-per-row resample; 4 edges in flight (16 lanes/edge); fuses next dinv
__device__ __forceinline__ void sample_ph(const uint16_t* __restrict__ cols,
                                          const uint32_t* __restrict__ deg,
                                          const float* __restrict__ z,
                                          TFKey kb, uint8_t* __restrict__ mask,
                                          float* __restrict__ dinv,
                                          int wid, int nw, int lane) {
  int g = lane >> 4, l = lane & 15;           // edge-group 0..3, lane-in-group
  for (int i = wid; i < NN; i += nw) {
    float4 zi = *(const float4*)(z + (size_t)i * 64 + 4 * l);
    uint32_t du = deg[i];
    uint32_t d = du < (uint32_t)CAP ? du : (uint32_t)CAP;
    const uint16_t* cr = cols + (size_t)i * CAP;
    uint8_t* mr = mask + (size_t)i * CAP;
    int cnt = 0;
    for (uint32_t base = 0; base < d; base += 4) {
      uint32_t s = base + (uint32_t)g;
      bool on = s < d;
      int j = 0;
      if (on) j = cr[s];
      float4 b = *(const float4*)(z + (size_t)j * 64 + 4 * l);
      double p = (double)zi.x * (double)b.x + (double)zi.y * (double)b.y
               + (double)zi.z * (double)b.z + (double)zi.w * (double)b.w;
      p += __shfl_xor(p, 1, 64);              // 16-lane tree: stays in group
      p += __shfl_xor(p, 2, 64);
      p += __shfl_xor(p, 4, 64);
      p += __shfl_xor(p, 8, 64);
      if (l == 0 && on) {
        float dot32 = (float)p;               // ref's f32 z@z.T entry
        float prob = (float)(1.0 / (1.0 + exp(-(double)dot32)));
        float u = tf_uniform(kb, (uint32_t)((i << 13) | j));
        uint8_t m = (u < prob) ? 1u : 0u;
        mr[s] = m;
        cnt += m;
      }
    }
    cnt += __shfl_xor(cnt, 16, 64);           // sum the 4 group leaders
    cnt += __shfl_xor(cnt, 32, 64);
    if (lane == 0) dinv[i] = (float)(1.0 / sqrt((double)(cnt + 1)));
  }
}

__global__ __launch_bounds__(256, 4) void fused(Params p) {
  cg::grid_group grid = cg::this_grid();
  const int tid = blockIdx.x * 256 + threadIdx.x;
  const int tot = gridDim.x * 256;
  const int lane = threadIdx.x & 63;
  const int wid = tid >> 6;
  const int nw = tot >> 6;

  // ---- P1: zero dense bitmask + deg; block 0 probes int64-vs-int32 ----
  for (int t = tid; t < NN * WPR / 4; t += tot)
    ((uint4*)p.dense)[t] = make_uint4(0u, 0u, 0u, 0u);
  for (int t = tid; t < NN; t += tot) p.deg[t] = 0u;
  if (blockIdx.x == 0) {
    const unsigned long long* q = (const unsigned long long*)p.ei;
    bool bad = false;
    for (int k = 0; k < 8; ++k)               // 2048 u64 samples: decisive
      bad |= (q[threadIdx.x * 8 + k] >= 8192ull);
    __shared__ uint32_t sh[4];
    unsigned long long b = __ballot(bad);
    if ((threadIdx.x & 63) == 0) sh[threadIdx.x >> 6] = (b != 0ull) ? 1u : 0u;
    __syncthreads();
    if (threadIdx.x == 0) p.flag[0] = sh[0] | sh[1] | sh[2] | sh[3];
  }
  grid.sync();

  // ---- P2: build dedup'd ELL (atomicOr claims, atomicAdd slots) ----
  {
    const uint32_t isI32 = *p.flag;
    for (int ed = tid; ed < NE; ed += tot) {
      int r, c;
      if (isI32) { r = p.ei[ed]; c = p.ei[ed + NE]; }
      else { const long long* q = (const long long*)p.ei; r = (int)q[ed]; c = (int)q[ed + NE]; }
      uint32_t bit = 1u << (c & 31);
      uint32_t old = atomicOr(&p.dense[(size_t)r * WPR + (c >> 5)], bit);
      if (!(old & bit)) {
        uint32_t s = atomicAdd(&p.deg[r], 1u);
        if (s < CAP) p.cols[(size_t)r * CAP + s] = (uint16_t)c; // memory safety
      }
    }
  }
  grid.sync();
  // dense dead; h/z overlay it from here on

  // ---- P3: gemm0 (x@W0) + dinv0 = rsqrt(deg+1) ----
  gemm_ph<128, 64>(p.x, p.W0, p.h, tid, tot);
  for (int t = tid; t < NN; t += tot)
    p.dinv[t] = (float)(1.0 / sqrt((double)(p.deg[t] + 1u)));
  grid.sync();

  // ---- P4: agg0 -> z ----
  agg_ph<64>(p.cols, p.deg, nullptr, p.h, p.dinv, p.b0, p.kd0, p.z, wid, nw, lane);
  grid.sync();

  // ---- P5: sample0 (mask, dinv1) || gemm1 (z@W1) — independent ----
  sample_ph(p.cols, p.deg, p.z, p.kb0, p.mask, p.dinv, wid, nw, lane);
  gemm_ph<64, 64>(p.z, p.W1, p.h, tid, tot);
  grid.sync();

  // ---- P6: agg1 -> z ----
  agg_ph<64>(p.cols, p.deg, p.mask, p.h, p.dinv, p.b1, p.kd1, p.z, wid, nw, lane);
  grid.sync();

  // ---- P7: sample1 (mask, dinv2) || gemm2 (z@W2) — independent ----
  sample_ph(p.cols, p.deg, p.z, p.kb1, p.mask, p.dinv, wid, nw, lane);
  gemm_ph<64, 32>(p.z, p.W2, p.h, tid, tot);
  grid.sync();

  // ---- P8: agg2 -> out ----
  agg_ph<32>(p.cols, p.deg, p.mask, p.h, p.dinv, p.b2, p.kd2, p.out, wid, nw, lane);
}

// =================== fallback pipeline (non-cooperative) ===================

__global__ __launch_bounds__(256) void k_init(const int* __restrict__ e,
                                              uint32_t* __restrict__ dense,
                                              uint32_t* __restrict__ deg,
                                              uint32_t* __restrict__ flag) {
  uint32_t t = blockIdx.x * 256 + threadIdx.x;
  ((uint4*)dense)[t] = make_uint4(0u, 0u, 0u, 0u);
  if (t < NN) deg[t] = 0u;
  if (blockIdx.x == 0) {
    const unsigned long long* p = (const unsigned long long*)e;
    bool bad = false;
    for (int q = 0; q < 8; ++q) bad |= (p[threadIdx.x * 8 + q] >= 8192ull);
    __shared__ uint32_t sh[4];
    unsigned long long b = __ballot(bad);
    if ((threadIdx.x & 63) == 0) sh[threadIdx.x >> 6] = (b != 0ull) ? 1u : 0u;
    __syncthreads();
    if (threadIdx.x == 0) flag[0] = sh[0] | sh[1] | sh[2] | sh[3];
  }
}

__global__ __launch_bounds__(256) void k_build(const int* __restrict__ e,
                                               const uint32_t* __restrict__ flag,
                                               uint32_t* __restrict__ dense,
                                               uint32_t* __restrict__ deg,
                                               uint16_t* __restrict__ cols) {
  int ed = blockIdx.x * 256 + threadIdx.x;
  int r, c;
  if (*flag) { r = e[ed]; c = e[ed + NE]; }
  else { const long long* p = (const long long*)e; r = (int)p[ed]; c = (int)p[ed + NE]; }
  uint32_t bit = 1u << (c & 31);
  uint32_t old = atomicOr(&dense[(size_t)r * WPR + (c >> 5)], bit);
  if (!(old & bit)) {
    uint32_t s = atomicAdd(&deg[r], 1u);
    if (s < CAP) cols[(size_t)r * CAP + s] = (uint16_t)c;
  }
}

template<int K, int N, bool DINV0>
__global__ __launch_bounds__(256) void k_dg(const float* __restrict__ A,
                                            const float* __restrict__ Wb,
                                            float* __restrict__ H,
                                            const uint32_t* __restrict__ deg,
                                            float* __restrict__ dinv) {
  constexpr int GB = NN * N / 256;
  if (blockIdx.x < GB) {
    int t = blockIdx.x * 256 + threadIdx.x;
    gemm_ph<K, N>(A, Wb, H, t, NN * N);       // single-trip grid-stride body
  } else if (DINV0) {
    int i = (blockIdx.x - GB) * 256 + threadIdx.x;
    dinv[i] = (float)(1.0 / sqrt((double)(deg[i] + 1u)));
  }
}

template<int D>
__global__ __launch_bounds__(256) void k_agg(const uint16_t* __restrict__ cols,
                                             const uint32_t* __restrict__ deg,
                                             const uint8_t* __restrict__ mask,
                                             const float* __restrict__ h,
                                             const float* __restrict__ dinv,
                                             const float* __restrict__ bias,
                                             TFKey kd, float* __restrict__ zout) {
  int lane = threadIdx.x & 63;
  int wid = blockIdx.x * 4 + (threadIdx.x >> 6);
  agg_ph<D>(cols, deg, mask, h, dinv, bias, kd, zout, wid, NN, lane);
}

__global__ __launch_bounds__(256) void k_sample(const uint16_t* __restrict__ cols,
                                                const uint32_t* __restrict__ deg,
                                                const float* __restrict__ z,
                                                TFKey kb,
                                                uint8_t* __restrict__ mask,
                                                float* __restrict__ dinv) {
  int lane = threadIdx.x & 63;
  int wid = blockIdx.x * 4 + (threadIdx.x >> 6);
  sample_ph(cols, deg, z, kb, mask, dinv, wid, NN, lane);
}

// ============================== launch =====================================

extern "C" void kernel_launch(void* const* d_in, const int* in_sizes, int n_in,
                              void* d_out, int out_size, void* d_ws, size_t ws_size,
                              hipStream_t stream) {
  (void)in_sizes; (void)n_in; (void)out_size; (void)ws_size;
  const float* x  = (const float*)d_in[0];
  const float* W0 = (const float*)d_in[1];
  const float* b0 = (const float*)d_in[2];
  const float* W1 = (const float*)d_in[3];
  const float* b1 = (const float*)d_in[4];
  const float* W2 = (const float*)d_in[5];
  const float* b2 = (const float*)d_in[6];
  const int* ei = (const int*)d_in[7];
  float* out = (float*)d_out;

  // Workspace (~10.8 MB): dense bitmask dies after build; f32 h/z overlay it
  uint8_t* base = (uint8_t*)d_ws;
  uint32_t* dense = (uint32_t*)(base);                       // [0, 8 MB) build only
  float* h        = (float*)(base);                          // [0, 2 MB) layers
  float* z        = (float*)(base + 2097152);                // [2, 4 MB)
  uint32_t* deg   = (uint32_t*)(base + 8388608);             // 32 KB
  uint16_t* cols  = (uint16_t*)(base + 8388608 + 32768);     // ELL cols, 1.5 MB
  uint8_t*  mask  = (uint8_t*)(base + 8388608 + 32768 + 1572864);           // 768 KB
  float*    dinv  = (float*)(base + 8388608 + 32768 + 1572864 + 786432);    // 32 KB
  uint32_t* flag  = (uint32_t*)(base + 8388608 + 32768 + 1572864 + 786432 + 32768);

  // JAX partitionable key chain: k_i = fold_in(key(42), i); kd@(0,0), kb@(0,1)
  TFKey kd[3], kb[3];
  for (uint32_t i = 0; i < 3; ++i) {
    uint32_t la, lb;
    tf2x32(0u, 42u, 0u, i, &la, &lb);
    tf2x32(la, lb, 0u, 0u, &kd[i].a, &kd[i].b);
    tf2x32(la, lb, 0u, 1u, &kb[i].a, &kb[i].b);
  }

  // One-time host queries (pure queries: capture-safe)
  static int coop = -1;
  static int nblk = 0;
  if (coop < 0) {
    int dev = 0; (void)hipGetDevice(&dev);
    int attr = 0;
    if (hipDeviceGetAttribute(&attr, hipDeviceAttributeCooperativeLaunch, dev) != hipSuccess)
      attr = 0;
    coop = attr;
    if (coop) {
      int per = 0;
      if (hipOccupancyMaxActiveBlocksPerMultiprocessor(
              &per, reinterpret_cast<const void*>(fused), 256, 0) != hipSuccess || per < 1)
        per = 1;
      int cus = 0;
      if (hipDeviceGetAttribute(&cus, hipDeviceAttributeMultiprocessorCount, dev) != hipSuccess || cus < 1)
        cus = 256;
      nblk = per * cus;
      if (nblk > 2048) nblk = 2048;           // ≤ 8192 rows; wave-per-row cap
      if (nblk < 1) nblk = 1;
    }
  }

  if (coop) {
    Params p = { x, W0, b0, W1, b1, W2, b2, ei, out,
                 dense, h, z, deg, cols, mask, dinv, flag,
                 kd[0], kb[0], kd[1], kb[1], kd[2] };
    void* args[] = { &p };
    (void)hipLaunchCooperativeKernel(reinterpret_cast<const void*>(fused),
                                     dim3(nblk), dim3(256), args, 0, stream);
    return;
  }

  // Fallback: round-1 10-node pipeline
  k_init <<<NN * WPR / (4 * 256), 256, 0, stream>>>(ei, dense, deg, flag);
  k_build<<<NE / 256, 256, 0, stream>>>(ei, flag, dense, deg, cols);
  k_dg<128, 64, true><<<NN * 64 / 256 + NN / 256, 256, 0, stream>>>(x, W0, h, deg, dinv);
  k_agg<64><<<NN / 4, 256, 0, stream>>>(cols, deg, nullptr, h, dinv, b0, kd[0], z);
  k_sample<<<NN / 4, 256, 0, stream>>>(cols, deg, z, kb[0], mask, dinv);
  k_dg<64, 64, false><<<NN * 64 / 256, 256, 0, stream>>>(z, W1, h, deg, dinv);
  k_agg<64><<<NN / 4, 256, 0, stream>>>(cols, deg, mask, h, dinv, b1, kd[1], z);
  k_sample<<<NN / 4, 256, 0, stream>>>(cols, deg, z, kb[1], mask, dinv);
  k_dg<64, 32, false><<<NN * 32 / 256, 256, 0, stream>>>(z, W2, h, deg, dinv);
  k_agg<32><<<NN / 4, 256, 0, stream>>>(cols, deg, mask, h, dinv, b2, kd[2], out);
}

// Round 3
// 219.439 us; speedup vs baseline: 4.1828x; 4.1828x over previous
//
#include <hip/hip_runtime.h>
#include <stdint.h>
#include <math.h>

#define NN 8192        // nodes
#define NE 262144      // edges
#define CAP 96         // ELL slots/row; max RAW multiplicity ~60 (mean 32, +11sigma)

struct TFKey { uint32_t a, b; };

// JAX threefry2x32 (rot 13,15,26,6 / 17,29,16,24; 20 rounds)
__host__ __device__ static inline void tf2x32(uint32_t k0, uint32_t k1,
                                              uint32_t x0, uint32_t x1,
                                              uint32_t* o0, uint32_t* o1) {
  uint32_t ks2 = k0 ^ k1 ^ 0x1BD11BDAu;
#define TF_ROT(x, r) (((x) << (r)) | ((x) >> (32 - (r))))
#define TF_R(r) { x0 += x1; x1 = TF_ROT(x1, r); x1 ^= x0; }
  x0 += k0; x1 += k1;
  TF_R(13) TF_R(15) TF_R(26) TF_R(6)
  x0 += k1;  x1 += ks2 + 1u;
  TF_R(17) TF_R(29) TF_R(16) TF_R(24)
  x0 += ks2; x1 += k0 + 2u;
  TF_R(13) TF_R(15) TF_R(26) TF_R(6)
  x0 += k0;  x1 += k1 + 3u;
  TF_R(17) TF_R(29) TF_R(16) TF_R(24)
  x0 += k1;  x1 += ks2 + 4u;
  TF_R(13) TF_R(15) TF_R(26) TF_R(6)
  x0 += ks2; x1 += k0 + 5u;
  *o0 = x0; *o1 = x1;
#undef TF_R
#undef TF_ROT
}

// JAX partitionable 32-bit random_bits at flat index n: bits = o0^o1 @ (0,n);
// uniform f32 = bitcast((bits>>9)|0x3f800000) - 1.0f  (exact 2^-23 grid)
__device__ static inline float tf_uniform(TFKey k, uint32_t n) {
  uint32_t o0, o1;
  tf2x32(k.a, k.b, 0u, n, &o0, &o1);
  uint32_t bits = o0 ^ o1;
  return __uint_as_float((bits >> 9) | 0x3f800000u) - 1.0f;
}

// ---- shared device bodies (bit-identical to the verified round-1 kernels) ----

// H = A@W, f64 acc -> f32 round; one output element per thread t
template<int K, int N>
__device__ __forceinline__ void gemm_elem(const float* __restrict__ A,
                                          const float* __restrict__ Wb,
                                          float* __restrict__ H, int t) {
  int i = t / N, c = t % N;
  double a0 = 0.0, a1 = 0.0;
#pragma unroll 8
  for (int k = 0; k < K; k += 2) {
    a0 += (double)A[(size_t)i * K + k] * (double)Wb[(size_t)k * N + c];
    a1 += (double)A[(size_t)i * K + k + 1] * (double)Wb[(size_t)(k + 1) * N + c];
  }
  H[t] = (float)(a0 + a1);
}

// z_i = dropout(relu(sum_j f32(di*dj)*h_j + f32(di*di)*h_i + b)); one row/wave
template<int D>
__device__ __forceinline__ void agg_row(const uint16_t* __restrict__ cols,
                                        const uint32_t* __restrict__ deg,
                                        const uint8_t* __restrict__ mask,
                                        const float* __restrict__ h,
                                        const float* __restrict__ dinv,
                                        const float* __restrict__ bias,
                                        TFKey kd, float* __restrict__ zout,
                                        int i, int lane) {
  bool act = lane < D;
  float di = dinv[i];
  uint32_t du = deg[i];
  uint32_t d = du < (uint32_t)CAP ? du : (uint32_t)CAP;
  const uint16_t* cr = cols + (size_t)i * CAP;
  const uint8_t* mr = mask ? mask + (size_t)i * CAP : (const uint8_t*)nullptr;
  double a0 = 0.0, a1 = 0.0;
  uint32_t s = 0;
  for (; s + 1 < d; s += 2) {                 // 2 accumulators: half the chain
    int j0 = cr[s], j1 = cr[s + 1];
    bool m0 = !mr || mr[s], m1 = !mr || mr[s + 1];
    if (act) {
      if (m0) { float c0 = di * dinv[j0]; a0 += (double)c0 * (double)h[(size_t)j0 * D + lane]; }
      if (m1) { float c1 = di * dinv[j1]; a1 += (double)c1 * (double)h[(size_t)j1 * D + lane]; }
    }
  }
  if (s < d && (!mr || mr[s]) && act) {
    int j = cr[s];
    float c = di * dinv[j];
    a0 += (double)c * (double)h[(size_t)j * D + lane];
  }
  if (act) {
    double acc = a0 + a1;
    float cI = di * di;                       // +I diagonal term, f32
    acc += (double)cI * (double)h[(size_t)i * D + lane];
    float sv = (float)acc;                    // matmul result rounded f32
    float pre = fmaxf(sv + bias[lane], 0.0f); // bias + relu (f32)
    float u = tf_uniform(kd, (uint32_t)(i * D + lane));
    zout[(size_t)i * D + lane] = (u < 0.9f) ? (pre / 0.9f) : 0.0f;
  }
}

// resample row i: 4 edges in flight (16 lanes/edge, float4/lane); f64 dot via
// shfl tree; survivor count fuses the NEXT layer's dinv
__device__ __forceinline__ void sample_row(const uint16_t* __restrict__ cols,
                                           const uint32_t* __restrict__ deg,
                                           const float* __restrict__ z,
                                           TFKey kb, uint8_t* __restrict__ mask,
                                           float* __restrict__ dinv,
                                           int i, int lane) {
  int g = lane >> 4, l = lane & 15;           // edge-group 0..3, lane-in-group
  float4 zi = *(const float4*)(z + (size_t)i * 64 + 4 * l);
  uint32_t du = deg[i];
  uint32_t d = du < (uint32_t)CAP ? du : (uint32_t)CAP;
  const uint16_t* cr = cols + (size_t)i * CAP;
  uint8_t* mr = mask + (size_t)i * CAP;
  int cnt = 0;
  for (uint32_t base = 0; base < d; base += 4) {
    uint32_t s = base + (uint32_t)g;
    bool on = s < d;
    int j = 0;
    if (on) j = cr[s];
    float4 b = *(const float4*)(z + (size_t)j * 64 + 4 * l);
    double p = (double)zi.x * (double)b.x + (double)zi.y * (double)b.y
             + (double)zi.z * (double)b.z + (double)zi.w * (double)b.w;
    p += __shfl_xor(p, 1, 64);                // 16-lane tree: stays in group
    p += __shfl_xor(p, 2, 64);
    p += __shfl_xor(p, 4, 64);
    p += __shfl_xor(p, 8, 64);
    if (l == 0 && on) {
      float dot32 = (float)p;                 // ref's f32 z@z.T entry
      float prob = (float)(1.0 / (1.0 + exp(-(double)dot32)));
      float u = tf_uniform(kb, (uint32_t)((i << 13) | j));
      uint8_t m = (u < prob) ? 1u : 0u;
      mr[s] = m;
      cnt += m;
    }
  }
  cnt += __shfl_xor(cnt, 16, 64);             // sum the 4 group leaders
  cnt += __shfl_xor(cnt, 32, 64);
  if (lane == 0) dinv[i] = (float)(1.0 / sqrt((double)(cnt + 1)));
}

// ==============================  kernels  ==================================

// zero deg; block 0 probes edge_index storage (int64 with vals<8192 vs int32)
__global__ __launch_bounds__(256) void k_init0(const int* __restrict__ e,
                                               uint32_t* __restrict__ deg,
                                               uint32_t* __restrict__ flag) {
  uint32_t t = blockIdx.x * 256 + threadIdx.x;
  deg[t] = 0u;                                 // grid = NN/256 blocks
  if (blockIdx.x == 0) {
    const unsigned long long* p = (const unsigned long long*)e;
    bool bad = false;
    for (int q = 0; q < 8; ++q)                // 2048 u64 samples: decisive
      bad |= (p[threadIdx.x * 8 + q] >= 8192ull);
    __shared__ uint32_t sh[4];
    unsigned long long b = __ballot(bad);
    if ((threadIdx.x & 63) == 0) sh[threadIdx.x >> 6] = (b != 0ull) ? 1u : 0u;
    __syncthreads();
    if (threadIdx.x == 0) flag[0] = sh[0] | sh[1] | sh[2] | sh[3];
  }
}

// blocks [0,GB0): gemm0 x@W0 -> h; blocks [GB0,GB0+NE/256): raw ELL scatter
// (dups included; per-row dedup happens in k_dedup). Independent workloads.
__global__ __launch_bounds__(256) void k_g0s(const float* __restrict__ x,
                                             const float* __restrict__ W0,
                                             float* __restrict__ h,
                                             const int* __restrict__ e,
                                             const uint32_t* __restrict__ flag,
                                             uint32_t* __restrict__ deg,
                                             uint16_t* __restrict__ cols) {
  constexpr int GB0 = NN * 64 / 256;
  if (blockIdx.x < GB0) {
    gemm_elem<128, 64>(x, W0, h, blockIdx.x * 256 + threadIdx.x);
  } else {
    int ed = (blockIdx.x - GB0) * 256 + threadIdx.x;
    int r, c;
    if (*flag) { r = e[ed]; c = e[ed + NE]; }
    else { const long long* p = (const long long*)e; r = (int)p[ed]; c = (int)p[ed + NE]; }
    uint32_t s = atomicAdd(&deg[r], 1u);
    if (s < CAP) cols[(size_t)r * CAP + s] = (uint16_t)c;   // memory safety
  }
}

// per-row dedup via 1KB LDS bitset per wave; in-place compaction (raw slots
// staged in registers first, so all reads precede all writes within the wave);
// writes unique deg + dinv0 = rsqrt(deg+1)
__global__ __launch_bounds__(256) void k_dedup(uint16_t* __restrict__ cols,
                                               uint32_t* __restrict__ deg,
                                               float* __restrict__ dinv) {
  __shared__ uint32_t bits[4][256];
  __shared__ uint32_t ucnt[4];
  int lane = threadIdx.x & 63;
  int wv = threadIdx.x >> 6;
  int i = blockIdx.x * 4 + wv;
  ((uint4*)bits[wv])[lane] = make_uint4(0u, 0u, 0u, 0u);
  if (lane == 0) ucnt[wv] = 0u;
  __syncthreads();
  uint32_t draw = deg[i];
  if (draw > (uint32_t)CAP) draw = (uint32_t)CAP;
  uint16_t* cr = cols + (size_t)i * CAP;
  // stage raw slots (<=96 => 2 per lane) in registers BEFORE any write
  uint32_t c0 = 0xFFFFFFFFu, c1 = 0xFFFFFFFFu;
  if ((uint32_t)lane < draw) c0 = cr[lane];
  if ((uint32_t)(lane + 64) < draw) c1 = cr[lane + 64];
  if (c0 != 0xFFFFFFFFu) {
    uint32_t bit = 1u << (c0 & 31);
    uint32_t old = atomicOr(&bits[wv][c0 >> 5], bit);
    if (!(old & bit)) { uint32_t p = atomicAdd(&ucnt[wv], 1u); cr[p] = (uint16_t)c0; }
  }
  if (c1 != 0xFFFFFFFFu) {
    uint32_t bit = 1u << (c1 & 31);
    uint32_t old = atomicOr(&bits[wv][c1 >> 5], bit);
    if (!(old & bit)) { uint32_t p = atomicAdd(&ucnt[wv], 1u); cr[p] = (uint16_t)c1; }
  }
  if (lane == 0) {
    uint32_t u = ucnt[wv];
    deg[i] = u;
    dinv[i] = (float)(1.0 / sqrt((double)(u + 1u)));
  }
}

template<int D>
__global__ __launch_bounds__(256) void k_agg(const uint16_t* __restrict__ cols,
                                             const uint32_t* __restrict__ deg,
                                             const uint8_t* __restrict__ mask,
                                             const float* __restrict__ h,
                                             const float* __restrict__ dinv,
                                             const float* __restrict__ bias,
                                             TFKey kd, float* __restrict__ zout) {
  int lane = threadIdx.x & 63;
  int i = blockIdx.x * 4 + (threadIdx.x >> 6);
  agg_row<D>(cols, deg, mask, h, dinv, bias, kd, zout, i, lane);
}

// blocks [0,GB): gemm z@W -> h (next layer); rest: resample rows (mask + next
// dinv). Independent: sample reads z/writes mask,dinv; gemm reads z/writes h.
template<int K, int N>
__global__ __launch_bounds__(256) void k_sg(const float* __restrict__ z,
                                            const float* __restrict__ Wb,
                                            float* __restrict__ h,
                                            const uint16_t* __restrict__ cols,
                                            const uint32_t* __restrict__ deg,
                                            TFKey kb,
                                            uint8_t* __restrict__ mask,
                                            float* __restrict__ dinv) {
  constexpr int GB = NN * N / 256;
  if (blockIdx.x < GB) {
    gemm_elem<K, N>(z, Wb, h, blockIdx.x * 256 + threadIdx.x);
  } else {
    int lane = threadIdx.x & 63;
    int i = (blockIdx.x - GB) * 4 + (threadIdx.x >> 6);
    sample_row(cols, deg, z, kb, mask, dinv, i, lane);
  }
}

// ==============================  launch  ===================================

extern "C" void kernel_launch(void* const* d_in, const int* in_sizes, int n_in,
                              void* d_out, int out_size, void* d_ws, size_t ws_size,
                              hipStream_t stream) {
  (void)in_sizes; (void)n_in; (void)out_size; (void)ws_size;
  const float* x  = (const float*)d_in[0];
  const float* W0 = (const float*)d_in[1];
  const float* b0 = (const float*)d_in[2];
  const float* W1 = (const float*)d_in[3];
  const float* b1 = (const float*)d_in[4];
  const float* W2 = (const float*)d_in[5];
  const float* b2 = (const float*)d_in[6];
  const int* ei = (const int*)d_in[7];
  float* out = (float*)d_out;

  // Workspace (~6.4 MB, no dense bitmask)
  uint8_t* base = (uint8_t*)d_ws;
  float* h        = (float*)(base);                          // [0, 2 MB)
  float* z        = (float*)(base + 2097152);                // [2, 4 MB)
  uint32_t* deg   = (uint32_t*)(base + 4194304);             // 32 KB
  uint16_t* cols  = (uint16_t*)(base + 4194304 + 32768);     // ELL cols, 1.5 MB
  uint8_t*  mask  = (uint8_t*)(base + 4194304 + 32768 + 1572864);           // 768 KB
  float*    dinv  = (float*)(base + 4194304 + 32768 + 1572864 + 786432);    // 32 KB
  uint32_t* flag  = (uint32_t*)(base + 4194304 + 32768 + 1572864 + 786432 + 32768);

  // JAX partitionable key chain: k_i = fold_in(key(42), i); kd@(0,0), kb@(0,1)
  TFKey kd[3], kb[3];
  for (uint32_t i = 0; i < 3; ++i) {
    uint32_t la, lb;
    tf2x32(0u, 42u, 0u, i, &la, &lb);
    tf2x32(la, lb, 0u, 0u, &kd[i].a, &kd[i].b);
    tf2x32(la, lb, 0u, 1u, &kb[i].a, &kb[i].b);
  }

  // 8-node pipeline; independent workloads share dispatches
  k_init0<<<NN / 256, 256, 0, stream>>>(ei, deg, flag);
  k_g0s  <<<NN * 64 / 256 + NE / 256, 256, 0, stream>>>(x, W0, h, ei, flag, deg, cols);
  k_dedup<<<NN / 4, 256, 0, stream>>>(cols, deg, dinv);
  k_agg<64><<<NN / 4, 256, 0, stream>>>(cols, deg, nullptr, h, dinv, b0, kd[0], z);
  k_sg<64, 64><<<NN * 64 / 256 + NN / 4, 256, 0, stream>>>(z, W1, h, cols, deg, kb[0], mask, dinv);
  k_agg<64><<<NN / 4, 256, 0, stream>>>(cols, deg, mask, h, dinv, b1, kd[1], z);
  k_sg<64, 32><<<NN * 32 / 256 + NN / 4, 256, 0, stream>>>(z, W2, h, cols, deg, kb[1], mask, dinv);
  k_agg<32><<<NN / 4, 256, 0, stream>>>(cols, deg, mask, h, dinv, b2, kd[2], out);
}